// Round 1
// 692.926 us; speedup vs baseline: 1.1143x; 1.1143x over previous
//
#include <hip/hip_runtime.h>
#include <stdint.h>

#define IN_DIM    1024
#define OUT_DIM   1024
#define ROWSTRIDE 1025        // x has INPUT_DIM + CONDITION_DIM columns
#define BATCH     32768
#define NBASIS    6
#define KTOT      (NBASIS * IN_DIM)   // 6144 : BT row stride (k = c*1024 + d)
#define KSTEPS    96                  // 6 c-blocks x 16 d-chunks of 64

typedef __bf16 bf16x8 __attribute__((ext_vector_type(8)));
typedef float  f32x4  __attribute__((ext_vector_type(4)));

__device__ inline unsigned short f2bf(float f) {
  union { float f; unsigned u; } v; v.f = f;
  unsigned u = v.u;
  return (unsigned short)((u + 0x7FFFu + ((u >> 16) & 1u)) >> 16);  // RNE
}

// ---------- prep 1: feats -> F bf16 [BATCH][1024]; basis -> bas_t fp32 [6][BATCH] ----------
__global__ void prep_f(const float* __restrict__ x,
                       unsigned short* __restrict__ F,
                       float* __restrict__ bas_t) {
  const int b = blockIdx.x;
  const int tid = threadIdx.x;            // 256
  const float* xr = x + (size_t)b * ROWSTRIDE;
  unsigned short* frow = F + (size_t)b * IN_DIM;

  #pragma unroll
  for (int k = 0; k < 2; ++k) {
    int d = k * 512 + tid * 2;
    union { unsigned short u[2]; unsigned int w; } p;
    p.u[0] = f2bf(xr[d]);
    p.u[1] = f2bf(xr[d + 1]);
    *(unsigned int*)(frow + d) = p.w;     // 4B-aligned coalesced store
  }

  if (tid < 6) {
    float t  = xr[IN_DIM];
    float r1 = fmaxf(t - 0.25f, 0.0f);
    float r2 = fmaxf(t - 0.50f, 0.0f);
    float r3 = fmaxf(t - 0.75f, 0.0f);
    float v = (tid == 0) ? 1.0f
            : (tid == 1) ? t
            : (tid == 2) ? t * t
            : (tid == 3) ? r1 * r1
            : (tid == 4) ? r2 * r2
            :              r3 * r3;
    bas_t[(size_t)tid * BATCH + b] = v;
  }
}

// ---------- prep 2: weight [6144][1024] fp32 -> BT [1024][6144] bf16 ----------
__global__ void prep_wt(const float* __restrict__ w, unsigned short* __restrict__ bt) {
  __shared__ unsigned short t[32][33];
  int k0 = blockIdx.x * 32;   // over KTOT
  int e0 = blockIdx.y * 32;   // over OUT_DIM
  int tid = threadIdx.x;      // 256
  #pragma unroll
  for (int p = tid; p < 1024; p += 256) {
    int kk = p >> 5, ee = p & 31;                       // coalesced read over ee
    t[ee][kk] = f2bf(w[(size_t)(k0 + kk) * OUT_DIM + e0 + ee]);
  }
  __syncthreads();
  #pragma unroll
  for (int p = tid; p < 1024; p += 256) {
    int ee = p >> 5, kk = p & 31;                       // coalesced write over kk
    bt[(size_t)(e0 + ee) * KTOT + k0 + kk] = t[ee][kk];
  }
}

// ---------- GEMM on compact F with deferred per-c basis flush ----------
// out[b][e] = sum_c bas[b][c] * ( sum_d F[b][d] * BT[e][c*1024+d] ) + bias[e]
__device__ inline void gload_lds16(const unsigned short* g, unsigned short* l) {
  __builtin_amdgcn_global_load_lds((const __attribute__((address_space(1))) void*)g,
                                   (__attribute__((address_space(3))) void*)l, 16, 0, 0);
}

__global__ __launch_bounds__(256, 2) void vcl_gemm(
    const unsigned short* __restrict__ F,    // [BATCH][1024] bf16
    const unsigned short* __restrict__ BT,   // [OUT_DIM][KTOT] bf16 W^T (k contiguous)
    const float* __restrict__ bas_t,         // [6][BATCH] fp32
    const float* __restrict__ bias,
    float* __restrict__ out) {
  // 32 KB tile space; reused as the fp32 epilogue buffer afterwards.
  __shared__ unsigned short smem[2 * 128 * 64];
  __shared__ __align__(16) float bas_lds[NBASIS * 128];   // 3 KB, written once
  unsigned short* sA = smem;
  unsigned short* sB = smem + 128 * 64;

  const int tid = threadIdx.x;
  const int bm0 = (blockIdx.x >> 3) * 128;
  const int bn0 = (blockIdx.x & 7) * 128;   // bn == XCD id (round-robin) -> B strip L2-resident

  const int wv   = tid >> 6;
  const int lane = tid & 63;
  const int lr   = lane >> 3;          // row within 8-row staging chunk
  const int kc   = (lane & 7) ^ lr;    // swizzled global k-chunk for this lane
  const int ln15 = lane & 15;
  const int quad = lane >> 4;
  const int wm   = wv >> 1, wn = wv & 1;
  const int cs0  = quad ^ (ln15 & 7);        // swizzled LDS slot, ks=0
  const int cs1  = (4 + quad) ^ (ln15 & 7);  // swizzled LDS slot, ks=1

  // basis table for this block's 128 rows: bas_lds[c*128 + row]
  for (int p = tid; p < NBASIS * 128; p += 256)
    bas_lds[p] = bas_t[(size_t)(p >> 7) * BATCH + bm0 + (p & 127)];

  // staging address bases (lane-dependent)
  const unsigned short* gA[4];
  const unsigned short* gB[4];
  unsigned short* lA[4];
  unsigned short* lB[4];
  #pragma unroll
  for (int wc = 0; wc < 4; ++wc) {
    int r = wv * 32 + wc * 8 + lr;
    gA[wc] = F  + (size_t)(bm0 + r) * IN_DIM + kc * 8;   // d-stride 1024 (compact)
    gB[wc] = BT + (size_t)(bn0 + r) * KTOT   + kc * 8;   // k-stride 6144
    lA[wc] = sA + (wv * 4 + wc) * 512;   // 1024 B per wave-instruction, lane*16 inside
    lB[wc] = sB + (wv * 4 + wc) * 512;
  }

  // bias for this thread's output columns
  float bias_j[4];
  #pragma unroll
  for (int j = 0; j < 4; ++j)
    bias_j[j] = bias[bn0 + wn * 64 + j * 16 + ln15];

  f32x4 acc[4][4]  = {};   // per-c partial (MFMA accumulator)
  f32x4 accO[4][4] = {};   // basis-weighted running sum

  // stage k-step 0
  #pragma unroll
  for (int wc = 0; wc < 4; ++wc) {
    gload_lds16(gA[wc], lA[wc]);
    gload_lds16(gB[wc], lB[wc]);
  }

  for (int t = 0; t < KSTEPS; ++t) {
    __syncthreads();   // staged tile visible (drains vmcnt)

    bf16x8 bfr2[2][4];
    #pragma unroll
    for (int j = 0; j < 4; ++j) {
      int nt = wn * 64 + j * 16 + ln15;
      bfr2[0][j] = *(const bf16x8*)(sB + nt * 64 + cs0 * 8);
      bfr2[1][j] = *(const bf16x8*)(sB + nt * 64 + cs1 * 8);
    }
    #pragma unroll
    for (int i = 0; i < 4; ++i) {
      int rowt = wm * 64 + i * 16 + ln15;
      bf16x8 af0 = *(const bf16x8*)(sA + rowt * 64 + cs0 * 8);
      bf16x8 af1 = *(const bf16x8*)(sA + rowt * 64 + cs1 * 8);
      #pragma unroll
      for (int j = 0; j < 4; ++j) {
        acc[i][j] = __builtin_amdgcn_mfma_f32_16x16x32_bf16(af0, bfr2[0][j], acc[i][j], 0, 0, 0);
        acc[i][j] = __builtin_amdgcn_mfma_f32_16x16x32_bf16(af1, bfr2[1][j], acc[i][j], 0, 0, 0);
      }
    }

    __syncthreads();   // all waves done reading tile t
    if (t + 1 < KSTEPS) {
      const int offA = ((t + 1) & 15) * 64;  // d wraps every 16 steps (per c-block)
      const int offB = (t + 1) * 64;         // k = c*1024 + d is monotone in t
      #pragma unroll
      for (int wc = 0; wc < 4; ++wc) {
        gload_lds16(gA[wc] + offA, lA[wc]);
        gload_lds16(gB[wc] + offB, lB[wc]);
      }
    }

    // end of c-block: accO += bas[row][c] * acc ; acc = 0   (overlaps in-flight loads)
    if ((t & 15) == 15) {
      const int c = t >> 4;
      #pragma unroll
      for (int i = 0; i < 4; ++i) {
        // acc element r of frag i maps to row = wm*64 + i*16 + quad*4 + r
        f32x4 bb = *(const f32x4*)(&bas_lds[c * 128 + wm * 64 + i * 16 + quad * 4]);
        #pragma unroll
        for (int j = 0; j < 4; ++j) {
          #pragma unroll
          for (int r = 0; r < 4; ++r)
            accO[i][j][r] += bb[r] * acc[i][j][r];
          acc[i][j] = (f32x4){0.0f, 0.0f, 0.0f, 0.0f};
        }
      }
    }
  }

  // ---- epilogue: reorganize via LDS for contiguous 512B row stores ----
  float* buf = (float*)smem;        // [32][132] fp32 = 16.9 KB, fits in 32 KB tile space
  const int ROWP = 132;
  const int erow = tid >> 3;        // 0..31 compact row
  const int echk = tid & 7;         // 16-col chunk
  const int grow_base = bm0 + (erow >> 4) * 64 + (erow & 15);
  const int gcol = bn0 + echk * 16;

  #pragma unroll
  for (int i = 0; i < 4; ++i) {
    __syncthreads();   // protect buf reuse (and tile reads on first pass)
    #pragma unroll
    for (int j = 0; j < 4; ++j) {
      int cr = wm * 16 + quad * 4;                  // compact row base for this lane
      int cc = wn * 64 + j * 16 + ln15;
      #pragma unroll
      for (int r = 0; r < 4; ++r)
        buf[(cr + r) * ROWP + cc] = accO[i][j][r] + bias_j[j];
    }
    __syncthreads();
    float* orow = out + (size_t)(grow_base + i * 16) * OUT_DIM + gcol;
    const float* brow = buf + erow * ROWP + echk * 16;
    #pragma unroll
    for (int e = 0; e < 4; ++e)
      *(f32x4*)(orow + e * 4) = *(const f32x4*)(brow + e * 4);
  }
}

extern "C" void kernel_launch(void* const* d_in, const int* in_sizes, int n_in,
                              void* d_out, int out_size, void* d_ws, size_t ws_size,
                              hipStream_t stream) {
  const float* x    = (const float*)d_in[0];
  const float* w    = (const float*)d_in[1];
  const float* bias = (const float*)d_in[2];
  float* out = (float*)d_out;

  // ws layout: F bf16 [32768][1024] = 64 MiB, BT bf16 [1024][6144] = 12 MiB, bas_t [6][32768] fp32
  unsigned short* F  = (unsigned short*)d_ws;
  unsigned short* BT = (unsigned short*)((char*)d_ws + (size_t)BATCH * IN_DIM * 2);
  float* bas_t = (float*)((char*)d_ws + (size_t)BATCH * IN_DIM * 2 + (size_t)OUT_DIM * KTOT * 2);

  prep_f<<<BATCH, 256, 0, stream>>>(x, F, bas_t);
  dim3 g2(KTOT / 32, OUT_DIM / 32);
  prep_wt<<<g2, 256, 0, stream>>>(w, BT);
  vcl_gemm<<<(BATCH / 128) * (OUT_DIM / 128), 256, 0, stream>>>(F, BT, bas_t, bias, out);
}